// Round 10
// baseline (216.780 us; speedup 1.0000x reference)
//
#include <hip/hip_runtime.h>

typedef float  f32x4  __attribute__((ext_vector_type(4)));
typedef __bf16 bf16x8 __attribute__((ext_vector_type(8)));
typedef unsigned short u16x8 __attribute__((ext_vector_type(8)));

__device__ __forceinline__ float rcpf(float x) { return __builtin_amdgcn_rcpf(x); }

// Pade[5/4] tanh (continued fraction), clamp +-3.5, max err ~1.8e-3.
// T(x) = x*(945 + 105x^2 + x^4) / (945 + 420x^2 + 15x^4)
__device__ __forceinline__ float ptanh(float x) {
    x = fminf(fmaxf(x, -3.5f), 3.5f);
    const float x2 = x * x;
    const float n  = __builtin_fmaf(x2, x2 + 105.0f, 945.0f);
    const float d  = __builtin_fmaf(x2, __builtin_fmaf(15.0f, x2, 420.0f), 945.0f);
    return x * n * rcpf(d);
}

// LSTM cell. Inputs pre-scaled: yi,yf,yo = 0.5*(pre+b) (sigmoid via
// 0.5+0.5*T(z/2)); yg = (pre+b) (tanh direct). No exp2 anywhere.
__device__ __forceinline__ float cell_update(float yi, float yf, float yg, float yo, float& c) {
    const float Ti = ptanh(yi), Tf = ptanh(yf), Tg = ptanh(yg), To = ptanh(yo);
    const float iv = __builtin_fmaf(0.5f, Ti, 0.5f);
    const float fv = __builtin_fmaf(0.5f, Tf, 0.5f);
    const float ov = __builtin_fmaf(0.5f, To, 0.5f);
    c = __builtin_fmaf(fv, c, iv * Tg);
    return ov * ptanh(c);                 // o * tanh(c)
}

// 16 batches/WG, 4 waves, grid 256 (1 WG/CU). One RAW barrier per timestep
// (lgkmcnt-only). Wave w owns N-tiles {w,w+4,w+8,w+12} -> lane (q,hi) holds
// all 4 gates of hidden he=16w+q for batches 4hi+j in its MFMA accs.
__global__ __launch_bounds__(256, 1) void lstm_fused(
    const float* __restrict__ x,      // [4096][256][16]
    const float* __restrict__ w_ih1,  // [256][16]
    const float* __restrict__ w_hh1,  // [256][64]
    const float* __restrict__ b_ih1, const float* __restrict__ b_hh1,
    const float* __restrict__ w_ih2,  // [4][64]
    const float* __restrict__ w_hh2,  // [4]
    const float* __restrict__ b_ih2, const float* __restrict__ b_hh2,
    const float* __restrict__ fc_w, const float* __restrict__ fc_b,
    float* __restrict__ out)          // [4096][256]
{
    __shared__ unsigned short A_h[2 * 16 * 64];        // 4KB dbuf h1 bf16 [buf][b][he], ^((b&7)<<4)
    __shared__ unsigned short Xc[2 * 16 * 16 * 32];    // 32KB dbuf x bf16 [buf][b][tt][k]
    __shared__ float Pre2[2][64];                      // dbuf layer-2 preacts [buf][b*4+g]
    __shared__ float Ybuf[16][16];                     // [b][tt] (wave-1 private)

    const int tid = threadIdx.x;
    const int wv  = tid >> 6;
    const int l   = tid & 63;
    const int q   = l & 15;
    const int hi  = l >> 4;
    const int b0  = blockIdx.x << 4;
    const int he  = (wv << 4) + q;
    const int sw  = (q & 7) << 4;

    ((u16x8*)A_h)[tid] = (u16x8){0,0,0,0,0,0,0,0};     // zero both A_h bufs (h_{-1}=0)

    // ---- B fragments, pre-scaled: 0.5 for sigmoid gates (i,f,o), 1.0 for g ----
    bf16x8 Bf[4][3];
    #pragma unroll
    for (int g = 0; g < 4; ++g) {
        const float sc = (g == 2) ? 1.0f : 0.5f;
        const int n = (g << 6) + (wv << 4) + q;
        #pragma unroll
        for (int ks = 0; ks < 3; ++ks) {
            bf16x8 tmp;
            #pragma unroll
            for (int j = 0; j < 8; ++j) {
                const int k = ks * 32 + hi * 8 + j;
                float v = 0.f;
                if (k < 64)      v = w_hh1[n * 64 + k];
                else if (k < 80) v = w_ih1[n * 16 + (k - 64)];
                tmp[j] = (__bf16)(sc * v);
            }
            Bf[g][ks] = tmp;
        }
    }
    bf16x8 B2[2];                                      // layer-2 input proj (wave 3)
    {
        const float sc2 = (q == 2) ? 1.0f : 0.5f;
        #pragma unroll
        for (int ks = 0; ks < 2; ++ks) {
            bf16x8 tmp;
            #pragma unroll
            for (int j = 0; j < 8; ++j) {
                const int k = ks * 32 + hi * 8 + j;
                const float v = (q < 4) ? w_ih2[q * 64 + k] : 0.f;
                tmp[j] = (__bf16)(sc2 * v);
            }
            B2[ks] = tmp;
        }
    }

    // layer-1 biases as scaled acc-init values
    float accb[4];
    #pragma unroll
    for (int g = 0; g < 4; ++g) {
        const float sc = (g == 2) ? 1.0f : 0.5f;
        accb[g] = sc * (b_ih1[(g << 6) + he] + b_hh1[(g << 6) + he]);
    }

    // layer-2 constants (scaled: 0.5 for i,f,o; 1.0 for g)
    const float w2si = 0.5f * w_hh2[0], w2sf = 0.5f * w_hh2[1];
    const float w2sg = 1.0f * w_hh2[2], w2so = 0.5f * w_hh2[3];
    const float nb2i = 0.5f * (b_ih2[0] + b_hh2[0]);
    const float nb2f = 0.5f * (b_ih2[1] + b_hh2[1]);
    const float tb2g = 1.0f * (b_ih2[2] + b_hh2[2]);
    const float nb2o = 0.5f * (b_ih2[3] + b_hh2[3]);
    const float fcw = fc_w[0], fcb = fc_b[0];

    // ---- x staging: thread (bx,part) owns x[b0+bx][t0+part][0..15] ----
    const int bx = tid >> 4, part = tid & 15;
    const int swx = (bx & 7) << 4;
    const unsigned xo0 = (unsigned)(bx * 1024 + (((part << 6) +  0) ^ swx));
    const unsigned xo1 = (unsigned)(bx * 1024 + (((part << 6) + 16) ^ swx));
    const unsigned xo2 = (unsigned)(bx * 1024 + (((part << 6) + 32) ^ swx));
    const unsigned xo3 = (unsigned)(bx * 1024 + (((part << 6) + 48) ^ swx));
    const float* xrow = x + (size_t)(b0 + bx) * 4096 + part * 16;

    f32x4 xq0, xq1, xq2, xq3;
    auto stage_x = [&](int bufoff) {
        bf16x8 lo, hw;
        #pragma unroll
        for (int j = 0; j < 4; ++j) {
            lo[j] = (__bf16)xq0[j]; lo[4 + j] = (__bf16)xq1[j];
            hw[j] = (__bf16)xq2[j]; hw[4 + j] = (__bf16)xq3[j];
        }
        const u16x8 z = {0,0,0,0,0,0,0,0};
        char* base = (char*)Xc + bufoff;
        *(u16x8*)(base + xo0) = __builtin_bit_cast(u16x8, lo);
        *(u16x8*)(base + xo1) = __builtin_bit_cast(u16x8, hw);
        *(u16x8*)(base + xo2) = z;
        *(u16x8*)(base + xo3) = z;
    };

    // prologue: stage chunk 0 into buf 0, prefetch chunk 1 into regs
    xq0 = ((const f32x4*)xrow)[0]; xq1 = ((const f32x4*)xrow)[1];
    xq2 = ((const f32x4*)xrow)[2]; xq3 = ((const f32x4*)xrow)[3];
    stage_x(0);
    {
        const float* p = xrow + 256;
        xq0 = ((const f32x4*)p)[0]; xq1 = ((const f32x4*)p)[1];
        xq2 = ((const f32x4*)p)[2]; xq3 = ((const f32x4*)p)[3];
    }

    // invariant addresses
    const unsigned ar0 = (unsigned)((q * 128 +      hi * 16) ^ sw);
    const unsigned ar1 = (unsigned)((q * 128 + 64 + hi * 16) ^ sw);
    unsigned awb[4];
    #pragma unroll
    for (int j = 0; j < 4; ++j) {
        const int b = (hi << 2) + j;
        awb[j] = (unsigned)(b * 128 + ((he * 2) ^ ((b & 7) << 4)));
    }

    float c1[4] = {0.f, 0.f, 0.f, 0.f};
    float h2 = 0.f, c2 = 0.f;

    __syncthreads();   // prologue sync

    #pragma unroll 2
    for (int t = 0; t < 256; ++t) {
        const int tt = t & 15;
        if (tt == 0 && t + 16 < 256) {
            stage_x(((((t >> 4) + 1) & 1)) << 14);     // next chunk -> idle buf
            if (t + 32 < 256) {
                const float* p = xrow + (t + 32) * 16;
                xq0 = ((const f32x4*)p)[0]; xq1 = ((const f32x4*)p)[1];
                xq2 = ((const f32x4*)p)[2]; xq3 = ((const f32x4*)p)[3];
            }
        }

        // A-frag reads: h_{t-1} from buf (t-1)&1, x from current chunk buf
        const int rb = ((t + 1) & 1) << 11;
        const u16x8 ra0 = *(const u16x8*)((const char*)A_h + rb + ar0);
        const u16x8 ra1 = *(const u16x8*)((const char*)A_h + rb + ar1);
        const u16x8 ra2 = *(const u16x8*)((const char*)Xc + (((t >> 4) & 1) << 14)
                                          + ((q * 1024 + (tt << 6) + (hi << 4)) ^ sw));

        // layer-2 + FC at lag 2 (wave 1, lanes 0..15 = batches)
        if (wv == 1 && t >= 2) {
            const int s = t - 2;
            if (l < 16) {
                const f32x4 p2 = *(const f32x4*)&Pre2[(t + 1) & 1][l << 2];
                const float zi = p2[0] + __builtin_fmaf(w2si, h2, nb2i);
                const float zf = p2[1] + __builtin_fmaf(w2sf, h2, nb2f);
                const float zg = p2[2] + __builtin_fmaf(w2sg, h2, tb2g);
                const float zo = p2[3] + __builtin_fmaf(w2so, h2, nb2o);
                h2 = cell_update(zi, zf, zg, zo, c2);
                Ybuf[l][s & 15] = __builtin_fmaf(fcw, h2, fcb);
            }
            if ((s & 15) == 15) {    // all 64 lanes flush 16 rows x 64B, coalesced
                float* op = out + (size_t)(b0 + (l >> 2)) * 256 + (s - 15) + ((l & 3) << 2);
                *(f32x4*)op = *(const f32x4*)&Ybuf[l >> 2][(l & 3) << 2];
            }
        }

        const bf16x8 a0 = __builtin_bit_cast(bf16x8, ra0);
        const bf16x8 a1 = __builtin_bit_cast(bf16x8, ra1);
        const bf16x8 a2 = __builtin_bit_cast(bf16x8, ra2);

        f32x4 g0 = {accb[0], accb[0], accb[0], accb[0]};
        f32x4 g1 = {accb[1], accb[1], accb[1], accb[1]};
        f32x4 g2 = {accb[2], accb[2], accb[2], accb[2]};
        f32x4 g3 = {accb[3], accb[3], accb[3], accb[3]};
        g0 = __builtin_amdgcn_mfma_f32_16x16x32_bf16(a2, Bf[0][2], g0, 0, 0, 0);
        g1 = __builtin_amdgcn_mfma_f32_16x16x32_bf16(a2, Bf[1][2], g1, 0, 0, 0);
        g2 = __builtin_amdgcn_mfma_f32_16x16x32_bf16(a2, Bf[2][2], g2, 0, 0, 0);
        g3 = __builtin_amdgcn_mfma_f32_16x16x32_bf16(a2, Bf[3][2], g3, 0, 0, 0);
        g0 = __builtin_amdgcn_mfma_f32_16x16x32_bf16(a0, Bf[0][0], g0, 0, 0, 0);
        g1 = __builtin_amdgcn_mfma_f32_16x16x32_bf16(a0, Bf[1][0], g1, 0, 0, 0);
        g2 = __builtin_amdgcn_mfma_f32_16x16x32_bf16(a0, Bf[2][0], g2, 0, 0, 0);
        g3 = __builtin_amdgcn_mfma_f32_16x16x32_bf16(a0, Bf[3][0], g3, 0, 0, 0);
        g0 = __builtin_amdgcn_mfma_f32_16x16x32_bf16(a1, Bf[0][1], g0, 0, 0, 0);
        g1 = __builtin_amdgcn_mfma_f32_16x16x32_bf16(a1, Bf[1][1], g1, 0, 0, 0);
        g2 = __builtin_amdgcn_mfma_f32_16x16x32_bf16(a1, Bf[2][1], g2, 0, 0, 0);
        g3 = __builtin_amdgcn_mfma_f32_16x16x32_bf16(a1, Bf[3][1], g3, 0, 0, 0);

        if (wv == 3) {   // layer-2 input projection of h_{t-1} -> Pre2[t&1]
            f32x4 p4 = {0.f, 0.f, 0.f, 0.f};
            p4 = __builtin_amdgcn_mfma_f32_16x16x32_bf16(a0, B2[0], p4, 0, 0, 0);
            p4 = __builtin_amdgcn_mfma_f32_16x16x32_bf16(a1, B2[1], p4, 0, 0, 0);
            if (q < 4) {
                #pragma unroll
                for (int r = 0; r < 4; ++r) Pre2[t & 1][((hi << 2) + r) * 4 + q] = p4[r];
            }
        }

        // elementwise: accs ARE the scaled preacts; write h_t to buf t&1
        char* AW = (char*)A_h + ((t & 1) << 11);
        #pragma unroll
        for (int j = 0; j < 4; ++j) {
            const float hv = cell_update(g0[j], g1[j], g2[j], g3[j], c1[j]);
            *(unsigned short*)(AW + awb[j]) = __builtin_bit_cast(unsigned short, (__bf16)hv);
        }

        // RAW barrier: only drain LDS ops (global loads/stores float across)
        asm volatile("s_waitcnt lgkmcnt(0)\n\ts_barrier" ::: "memory");
    }

    // ---- epilogue: layer-2 steps s=254 (Pre2[1]) and s=255 (fresh proj h_255) ----
    if (wv == 3) {
        const u16x8 ra0 = *(const u16x8*)((const char*)A_h + 2048 + ar0);
        const u16x8 ra1 = *(const u16x8*)((const char*)A_h + 2048 + ar1);
        f32x4 p4 = {0.f, 0.f, 0.f, 0.f};
        p4 = __builtin_amdgcn_mfma_f32_16x16x32_bf16(__builtin_bit_cast(bf16x8, ra0), B2[0], p4, 0, 0, 0);
        p4 = __builtin_amdgcn_mfma_f32_16x16x32_bf16(__builtin_bit_cast(bf16x8, ra1), B2[1], p4, 0, 0, 0);
        if (q < 4) {
            #pragma unroll
            for (int r = 0; r < 4; ++r) Pre2[0][((hi << 2) + r) * 4 + q] = p4[r];
        }
    }
    __syncthreads();
    if (wv == 1) {
        if (l < 16) {
            #pragma unroll
            for (int e = 0; e < 2; ++e) {   // e=0 -> s=254 (Pre2[1]), e=1 -> s=255 (Pre2[0])
                const f32x4 p2 = *(const f32x4*)&Pre2[1 - e][l << 2];
                const float zi = p2[0] + __builtin_fmaf(w2si, h2, nb2i);
                const float zf = p2[1] + __builtin_fmaf(w2sf, h2, nb2f);
                const float zg = p2[2] + __builtin_fmaf(w2sg, h2, tb2g);
                const float zo = p2[3] + __builtin_fmaf(w2so, h2, nb2o);
                h2 = cell_update(zi, zf, zg, zo, c2);
                Ybuf[l][14 + e] = __builtin_fmaf(fcw, h2, fcb);
            }
        }
        float* op = out + (size_t)(b0 + (l >> 2)) * 256 + 240 + ((l & 3) << 2);
        *(f32x4*)op = *(const f32x4*)&Ybuf[l >> 2][(l & 3) << 2];
    }
}

extern "C" void kernel_launch(void* const* d_in, const int* in_sizes, int n_in,
                              void* d_out, int out_size, void* d_ws, size_t ws_size,
                              hipStream_t stream) {
    (void)in_sizes; (void)n_in; (void)out_size; (void)d_ws; (void)ws_size;
    const float* x     = (const float*)d_in[0];
    const float* w_ih1 = (const float*)d_in[1];
    const float* w_hh1 = (const float*)d_in[2];
    const float* b_ih1 = (const float*)d_in[3];
    const float* b_hh1 = (const float*)d_in[4];
    const float* w_ih2 = (const float*)d_in[5];
    const float* w_hh2 = (const float*)d_in[6];
    const float* b_ih2 = (const float*)d_in[7];
    const float* b_hh2 = (const float*)d_in[8];
    const float* fc_w  = (const float*)d_in[9];
    const float* fc_b  = (const float*)d_in[10];
    lstm_fused<<<dim3(256), dim3(256), 0, stream>>>(
        x, w_ih1, w_hh1, b_ih1, b_hh1, w_ih2, w_hh2, b_ih2, b_hh2, fc_w, fc_b,
        (float*)d_out);
}

// Round 11
// 167.158 us; speedup vs baseline: 1.2969x; 1.2969x over previous
//
#include <hip/hip_runtime.h>

typedef float  f32x4  __attribute__((ext_vector_type(4)));
typedef __bf16 bf16x8 __attribute__((ext_vector_type(8)));
typedef unsigned short u16x8 __attribute__((ext_vector_type(8)));

#define NL2E (-1.44269504088896f)   // -log2(e)
#define TL2E ( 2.88539008177793f)   // 2*log2(e)

__device__ __forceinline__ float rcpf(float x) { return __builtin_amdgcn_rcpf(x); }
__device__ __forceinline__ float ex2(float x)  { return __builtin_amdgcn_exp2f(x); }

// LSTM cell from pre-scaled gate args (zi,zf,zo = -log2e*pre, zg = 2log2e*pre).
// 3-rcp form: i*g=(Eg-1)/((1+Ei)(1+Eg)), f=1/(1+Ef), o*tanh(c)=(Ec-1)/((1+Eo)(1+Ec)).
__device__ __forceinline__ float cell_update(float zi, float zf, float zg, float zo, float& c) {
    const float Ei = ex2(zi), Ef = ex2(zf), Eg = ex2(zg), Eo = ex2(zo);
    const float ig = (Eg - 1.0f) * rcpf((1.0f + Ei) * (1.0f + Eg));
    const float fv = rcpf(1.0f + Ef);
    c = __builtin_fmaf(fv, c, ig);
    const float zc = fminf(fmaxf(TL2E * c, -60.0f), 60.0f);
    const float Ec = ex2(zc);
    return (Ec - 1.0f) * rcpf((1.0f + Eo) * (1.0f + Ec));   // o*tanh(c)
}

// 16 batches/WG, 4 waves, grid 256 (1 WG/CU), one raw lgkm barrier/step.
// Wave w owns N-tiles {w,w+4,w+8,w+12}; lane (q,hi) holds all 4 gates of
// hidden he=16w+q for batches 4hi+j in its MFMA accs.
// Layer-1 biases ride the MFMA via K-slot 80: A has a constant 1.0 there
// (Xc pad, written once), B has the scaled bias -> acc init is a hoisted zero.
__global__ __launch_bounds__(256, 1) void lstm_fused(
    const float* __restrict__ x,      // [4096][256][16]
    const float* __restrict__ w_ih1,  // [256][16]
    const float* __restrict__ w_hh1,  // [256][64]
    const float* __restrict__ b_ih1, const float* __restrict__ b_hh1,
    const float* __restrict__ w_ih2,  // [4][64]
    const float* __restrict__ w_hh2,  // [4]
    const float* __restrict__ b_ih2, const float* __restrict__ b_hh2,
    const float* __restrict__ fc_w, const float* __restrict__ fc_b,
    float* __restrict__ out)          // [4096][256]
{
    __shared__ unsigned short A_h[2 * 16 * 64];        // 4KB dbuf h1 bf16 [buf][b][he], ^((b&7)<<4)
    __shared__ unsigned short Xc[2 * 16 * 16 * 32];    // 32KB dbuf x bf16 [buf][b][tt][k']
    __shared__ float Pre2[2][64];                      // dbuf layer-2 preacts [buf][b*4+g]
    __shared__ float Ybuf[16][16];                     // [b][tt] (wave-1 private)

    const int tid = threadIdx.x;
    const int wv  = tid >> 6;
    const int l   = tid & 63;
    const int q   = l & 15;
    const int hi  = l >> 4;
    const int b0  = blockIdx.x << 4;
    const int he  = (wv << 4) + q;
    const int sw  = (q & 7) << 4;
    const u16x8 z8 = {0,0,0,0,0,0,0,0};

    ((u16x8*)A_h)[tid] = z8;                           // zero both A_h bufs (h_{-1}=0)
    {   // init Xc pad halves once (both bufs): k'=16 -> bf16(1.0), rest 0.
        // 512 pad rows total; each thread handles 2.
        const u16x8 pad1 = {0x3F80, 0, 0, 0, 0, 0, 0, 0};
        #pragma unroll
        for (int r = 0; r < 2; ++r) {
            const int idx = (tid << 1) + r;            // 0..511
            const int buf = idx >> 8, pb = (idx >> 4) & 15, ptt = idx & 15;
            char* base = (char*)Xc + (buf << 14) + pb * 1024;
            const int swp = (pb & 7) << 4;
            *(u16x8*)(base + ((ptt * 64 + 32) ^ swp)) = pad1;
            *(u16x8*)(base + ((ptt * 64 + 48) ^ swp)) = z8;
        }
    }

    // ---- B fragments, pre-scaled; bias in k=80 row ----
    bf16x8 Bf[4][3];
    #pragma unroll
    for (int g = 0; g < 4; ++g) {
        const float sc = (g == 2) ? TL2E : NL2E;
        const int n = (g << 6) + (wv << 4) + q;
        #pragma unroll
        for (int ks = 0; ks < 3; ++ks) {
            bf16x8 tmp;
            #pragma unroll
            for (int j = 0; j < 8; ++j) {
                const int k = ks * 32 + hi * 8 + j;
                float v = 0.f;
                if (k < 64)       v = w_hh1[n * 64 + k];
                else if (k < 80)  v = w_ih1[n * 16 + (k - 64)];
                else if (k == 80) v = b_ih1[n] + b_hh1[n];   // pairs with A's 1.0
                tmp[j] = (__bf16)(sc * v);
            }
            Bf[g][ks] = tmp;
        }
    }
    bf16x8 B2[2];                                      // layer-2 input proj (wave 3; K<64 only)
    {
        const float sc2 = (q == 2) ? TL2E : NL2E;
        #pragma unroll
        for (int ks = 0; ks < 2; ++ks) {
            bf16x8 tmp;
            #pragma unroll
            for (int j = 0; j < 8; ++j) {
                const int k = ks * 32 + hi * 8 + j;
                const float v = (q < 4) ? w_ih2[q * 64 + k] : 0.f;
                tmp[j] = (__bf16)(sc2 * v);
            }
            B2[ks] = tmp;
        }
    }

    // layer-2 constants (scaled)
    const float w2si = NL2E * w_hh2[0], w2sf = NL2E * w_hh2[1];
    const float w2sg = TL2E * w_hh2[2], w2so = NL2E * w_hh2[3];
    const float nb2i = NL2E * (b_ih2[0] + b_hh2[0]);
    const float nb2f = NL2E * (b_ih2[1] + b_hh2[1]);
    const float tb2g = TL2E * (b_ih2[2] + b_hh2[2]);
    const float nb2o = NL2E * (b_ih2[3] + b_hh2[3]);
    const float fcw = fc_w[0], fcb = fc_b[0];

    // ---- x staging: thread (bx,part) owns x[b0+bx][t0+part][0..15] ----
    const int bx = tid >> 4, part = tid & 15;
    const int swx = (bx & 7) << 4;
    const unsigned xo0 = (unsigned)(bx * 1024 + (((part << 6) +  0) ^ swx));
    const unsigned xo1 = (unsigned)(bx * 1024 + (((part << 6) + 16) ^ swx));
    const float* xrow = x + (size_t)(b0 + bx) * 4096 + part * 16;

    f32x4 xq0, xq1, xq2, xq3;
    auto stage_x = [&](int bufoff) {   // data halves only; pads persist
        bf16x8 lo, hw;
        #pragma unroll
        for (int j = 0; j < 4; ++j) {
            lo[j] = (__bf16)xq0[j]; lo[4 + j] = (__bf16)xq1[j];
            hw[j] = (__bf16)xq2[j]; hw[4 + j] = (__bf16)xq3[j];
        }
        char* base = (char*)Xc + bufoff;
        *(u16x8*)(base + xo0) = __builtin_bit_cast(u16x8, lo);
        *(u16x8*)(base + xo1) = __builtin_bit_cast(u16x8, hw);
    };

    // prologue: stage chunk 0 into buf 0, prefetch chunk 1 into regs
    xq0 = ((const f32x4*)xrow)[0]; xq1 = ((const f32x4*)xrow)[1];
    xq2 = ((const f32x4*)xrow)[2]; xq3 = ((const f32x4*)xrow)[3];
    stage_x(0);
    {
        const float* p = xrow + 256;
        xq0 = ((const f32x4*)p)[0]; xq1 = ((const f32x4*)p)[1];
        xq2 = ((const f32x4*)p)[2]; xq3 = ((const f32x4*)p)[3];
    }

    // invariant addresses
    const unsigned ar0 = (unsigned)((q * 128 +      hi * 16) ^ sw);
    const unsigned ar1 = (unsigned)((q * 128 + 64 + hi * 16) ^ sw);
    unsigned awb[4];
    #pragma unroll
    for (int j = 0; j < 4; ++j) {
        const int b = (hi << 2) + j;
        awb[j] = (unsigned)(b * 128 + ((he * 2) ^ ((b & 7) << 4)));
    }

    float c1[4] = {0.f, 0.f, 0.f, 0.f};
    float h2 = 0.f, c2 = 0.f;
    const f32x4 kz = {0.f, 0.f, 0.f, 0.f};   // loop-invariant acc init (bias rides K=80)

    __syncthreads();   // prologue sync (full drain once is fine)

    // x-fragment for t=0 carried in regs
    u16x8 ra2cur = *(const u16x8*)((const char*)Xc + ((q * 1024 + (hi << 4)) ^ sw));

    #pragma unroll 2
    for (int t = 0; t < 256; ++t) {
        const int tt = t & 15;
        if (tt == 0 && t + 16 < 256) {
            stage_x(((((t >> 4) + 1) & 1)) << 14);     // next chunk -> idle buf
            if (t + 32 < 256) {
                const float* p = xrow + (t + 32) * 16;
                xq0 = ((const f32x4*)p)[0]; xq1 = ((const f32x4*)p)[1];
                xq2 = ((const f32x4*)p)[2]; xq3 = ((const f32x4*)p)[3];
            }
        }

        // h_{t-1} fragment reads (the only loads the MFMA must wait on)
        const int rb = ((t + 1) & 1) << 11;
        const u16x8 ra0 = *(const u16x8*)((const char*)A_h + rb + ar0);
        const u16x8 ra1 = *(const u16x8*)((const char*)A_h + rb + ar1);
        // pre-read x-fragment for t+1 (its chunk's staging barrier passed >=1 step ago)
        const int tn = (t < 255) ? t + 1 : t;
        const u16x8 ra2nxt = *(const u16x8*)((const char*)Xc + (((tn >> 4) & 1) << 14)
                               + ((q * 1024 + ((tn & 15) << 6) + (hi << 4)) ^ sw));
        // wave-1: issue layer-2 preact read early (consumed in MFMA shadow)
        f32x4 p2;
        if (wv == 1) p2 = *(const f32x4*)&Pre2[(t + 1) & 1][(l & 15) << 2];

        // ---- MFMA: a2 (regs, no wait) first, then a0, a1 ----
        const bf16x8 a2 = __builtin_bit_cast(bf16x8, ra2cur);
        f32x4 g0 = kz, g1 = kz, g2 = kz, g3 = kz;
        g0 = __builtin_amdgcn_mfma_f32_16x16x32_bf16(a2, Bf[0][2], g0, 0, 0, 0);
        g1 = __builtin_amdgcn_mfma_f32_16x16x32_bf16(a2, Bf[1][2], g1, 0, 0, 0);
        g2 = __builtin_amdgcn_mfma_f32_16x16x32_bf16(a2, Bf[2][2], g2, 0, 0, 0);
        g3 = __builtin_amdgcn_mfma_f32_16x16x32_bf16(a2, Bf[3][2], g3, 0, 0, 0);
        const bf16x8 a0 = __builtin_bit_cast(bf16x8, ra0);
        g0 = __builtin_amdgcn_mfma_f32_16x16x32_bf16(a0, Bf[0][0], g0, 0, 0, 0);
        g1 = __builtin_amdgcn_mfma_f32_16x16x32_bf16(a0, Bf[1][0], g1, 0, 0, 0);
        g2 = __builtin_amdgcn_mfma_f32_16x16x32_bf16(a0, Bf[2][0], g2, 0, 0, 0);
        g3 = __builtin_amdgcn_mfma_f32_16x16x32_bf16(a0, Bf[3][0], g3, 0, 0, 0);
        const bf16x8 a1 = __builtin_bit_cast(bf16x8, ra1);
        g0 = __builtin_amdgcn_mfma_f32_16x16x32_bf16(a1, Bf[0][1], g0, 0, 0, 0);
        g1 = __builtin_amdgcn_mfma_f32_16x16x32_bf16(a1, Bf[1][1], g1, 0, 0, 0);
        g2 = __builtin_amdgcn_mfma_f32_16x16x32_bf16(a1, Bf[2][1], g2, 0, 0, 0);
        g3 = __builtin_amdgcn_mfma_f32_16x16x32_bf16(a1, Bf[3][1], g3, 0, 0, 0);

        if (wv == 3) {   // layer-2 input projection of h_{t-1} -> Pre2[t&1]
            f32x4 p4 = kz;
            p4 = __builtin_amdgcn_mfma_f32_16x16x32_bf16(a0, B2[0], p4, 0, 0, 0);
            p4 = __builtin_amdgcn_mfma_f32_16x16x32_bf16(a1, B2[1], p4, 0, 0, 0);
            if (q < 4) {
                #pragma unroll
                for (int r = 0; r < 4; ++r) Pre2[t & 1][((hi << 2) + r) * 4 + q] = p4[r];
            }
        }

        // ---- wave-1 layer-2 + FC, in the main-MFMA pipe shadow ----
        if (wv == 1 && t >= 2) {
            const int s = t - 2;
            if (l < 16) {
                const float zi = p2[0] + __builtin_fmaf(w2si, h2, nb2i);
                const float zf = p2[1] + __builtin_fmaf(w2sf, h2, nb2f);
                const float zg = p2[2] + __builtin_fmaf(w2sg, h2, tb2g);
                const float zo = p2[3] + __builtin_fmaf(w2so, h2, nb2o);
                h2 = cell_update(zi, zf, zg, zo, c2);
                Ybuf[l][s & 15] = __builtin_fmaf(fcw, h2, fcb);
            }
            if ((s & 15) == 15) {   // all 64 lanes flush 16 rows x 64B, coalesced
                float* op = out + (size_t)(b0 + (l >> 2)) * 256 + (s - 15) + ((l & 3) << 2);
                *(f32x4*)op = *(const f32x4*)&Ybuf[l >> 2][(l & 3) << 2];
            }
        }

        // ---- elementwise: accs ARE the scaled preacts (bias included) ----
        char* AW = (char*)A_h + ((t & 1) << 11);
        #pragma unroll
        for (int j = 0; j < 4; ++j) {
            const float hv = cell_update(g0[j], g1[j], g2[j], g3[j], c1[j]);
            *(unsigned short*)(AW + awb[j]) = __builtin_bit_cast(unsigned short, (__bf16)hv);
        }

        ra2cur = ra2nxt;
        // raw barrier: only drain LDS ops (global loads/stores float across)
        asm volatile("s_waitcnt lgkmcnt(0)\n\ts_barrier" ::: "memory");
    }

    // ---- epilogue: layer-2 steps s=254 (Pre2[1]) and s=255 (fresh proj h_255) ----
    if (wv == 3) {
        const u16x8 ra0 = *(const u16x8*)((const char*)A_h + 2048 + ar0);
        const u16x8 ra1 = *(const u16x8*)((const char*)A_h + 2048 + ar1);
        f32x4 p4 = {0.f, 0.f, 0.f, 0.f};
        p4 = __builtin_amdgcn_mfma_f32_16x16x32_bf16(__builtin_bit_cast(bf16x8, ra0), B2[0], p4, 0, 0, 0);
        p4 = __builtin_amdgcn_mfma_f32_16x16x32_bf16(__builtin_bit_cast(bf16x8, ra1), B2[1], p4, 0, 0, 0);
        if (q < 4) {
            #pragma unroll
            for (int r = 0; r < 4; ++r) Pre2[0][((hi << 2) + r) * 4 + q] = p4[r];
        }
    }
    __syncthreads();
    if (wv == 1) {
        if (l < 16) {
            #pragma unroll
            for (int e = 0; e < 2; ++e) {   // e=0 -> s=254 (Pre2[1]), e=1 -> s=255 (Pre2[0])
                const f32x4 p2 = *(const f32x4*)&Pre2[1 - e][l << 2];
                const float zi = p2[0] + __builtin_fmaf(w2si, h2, nb2i);
                const float zf = p2[1] + __builtin_fmaf(w2sf, h2, nb2f);
                const float zg = p2[2] + __builtin_fmaf(w2sg, h2, tb2g);
                const float zo = p2[3] + __builtin_fmaf(w2so, h2, nb2o);
                h2 = cell_update(zi, zf, zg, zo, c2);
                Ybuf[l][14 + e] = __builtin_fmaf(fcw, h2, fcb);
            }
        }
        float* op = out + (size_t)(b0 + (l >> 2)) * 256 + 240 + ((l & 3) << 2);
        *(f32x4*)op = *(const f32x4*)&Ybuf[l >> 2][(l & 3) << 2];
    }
}

extern "C" void kernel_launch(void* const* d_in, const int* in_sizes, int n_in,
                              void* d_out, int out_size, void* d_ws, size_t ws_size,
                              hipStream_t stream) {
    (void)in_sizes; (void)n_in; (void)out_size; (void)d_ws; (void)ws_size;
    const float* x     = (const float*)d_in[0];
    const float* w_ih1 = (const float*)d_in[1];
    const float* w_hh1 = (const float*)d_in[2];
    const float* b_ih1 = (const float*)d_in[3];
    const float* b_hh1 = (const float*)d_in[4];
    const float* w_ih2 = (const float*)d_in[5];
    const float* w_hh2 = (const float*)d_in[6];
    const float* b_ih2 = (const float*)d_in[7];
    const float* b_hh2 = (const float*)d_in[8];
    const float* fc_w  = (const float*)d_in[9];
    const float* fc_b  = (const float*)d_in[10];
    lstm_fused<<<dim3(256), dim3(256), 0, stream>>>(
        x, w_ih1, w_hh1, b_ih1, b_hh1, w_ih2, w_hh2, b_ih2, b_hh2, fc_w, fc_b,
        (float*)d_out);
}